// Round 14
// baseline (142.994 us; speedup 1.0000x reference)
//
#include <hip/hip_runtime.h>
#include <hip/hip_fp16.h>
#include <math.h>

constexpr int IN_F = 128;
constexpr int HID  = 64;
constexpr int OUT_F = 10;
constexpr int NG   = 256;
constexpr int BSH  = 7;            // 128 nodes per bucket
constexpr int BNODES = 1 << BSH;
constexpr int CAP  = 3072;         // per-bucket edge capacity (mean ~2046)
constexpr int NBUK_MAX = 1024;     // supports N <= 131072
constexpr int EPB  = 8192;         // edges per bucket-sort block
constexpr int EMAX = 1024;         // LDS edge-stage capacity per layer block
constexpr int NLAYER = 3;

typedef _Float16 half8 __attribute__((ext_vector_type(8)));
typedef float f32x4 __attribute__((ext_vector_type(4)));

// ---- int32/int64 detection + gcur zeroing + W->f16^T pre-convert ----
__global__ void k_detect(const unsigned int* w, int nwords, int* flag,
                         int* gcur, int nbuk,
                         const float* __restrict__ convw,
                         unsigned short* __restrict__ w16t) {
    __shared__ int nz;
    if (threadIdx.x == 0) nz = 0;
    for (int t = threadIdx.x; t < nbuk; t += 256) gcur[t] = 0;
    // w16t[layer][n][k] = (f16) convw[layer][k][n]
    for (int idx = threadIdx.x; idx < NLAYER * HID * HID; idx += 256) {
        int layer = idx >> 12;
        int rem = idx & 4095;
        int n = rem >> 6, k = rem & 63;
        w16t[idx] = __half_as_ushort(__float2half(convw[layer * 4096 + k * HID + n]));
    }
    __syncthreads();
    int seen = 0;
    for (int i = 1 + 2 * (int)threadIdx.x; i < nwords; i += 2 * (int)blockDim.x)
        if (w[i] != 0u) seen = 1;
    if (seen) atomicOr(&nz, 1);
    __syncthreads();
    if (threadIdx.x == 0) *flag = (nz == 0) ? 1 : 0;
}

__device__ __forceinline__ int ld_idx(const void* p, long long i, int is64) {
    return is64 ? (int)((const long long*)p)[i] : ((const int*)p)[i];
}

// ---- pass 1: block-level counting sort into contiguous per-bucket regions ----
__global__ __launch_bounds__(1024) void k_bucket2(const void* eidx, const int* f64,
                                                  int E, int nbuk,
                                                  int* gcur, unsigned* bucketed) {
    __shared__ int lhist[NBUK_MAX];
    __shared__ int lofs[NBUK_MAX];
    __shared__ int lcur[NBUK_MAX];
    __shared__ unsigned stage[EPB];
    __shared__ unsigned short sbid[EPB];
    int tid = threadIdx.x;
    long long base = (long long)blockIdx.x * EPB;
    int nval = (int)min((long long)EPB, (long long)E - base);
    int is64 = *f64;
    lhist[tid] = 0; lcur[tid] = 0;
    __syncthreads();
    unsigned pv[8]; int bv[8];
    #pragma unroll
    for (int j = 0; j < 8; ++j) {
        long long e = base + j * 1024 + tid;
        if (e < E) {
            int r = ld_idx(eidx, e, is64);
            int c = ld_idx(eidx, (long long)E + e, is64);
            int b = c >> BSH;
            pv[j] = (unsigned)r | ((unsigned)(c & (BNODES - 1)) << 20);
            bv[j] = b;
            atomicAdd(&lhist[b], 1);
        } else bv[j] = -1;
    }
    __syncthreads();
    lofs[tid] = lhist[tid];
    __syncthreads();
    for (int off = 1; off < NBUK_MAX; off <<= 1) {
        int v = (tid >= off) ? lofs[tid - off] : 0;
        __syncthreads();
        lofs[tid] += v;
        __syncthreads();
    }
    int cnt = lhist[tid];
    if (tid < nbuk && cnt > 0)
        lhist[tid] = atomicAdd(&gcur[tid], cnt);
    #pragma unroll
    for (int j = 0; j < 8; ++j) {
        if (bv[j] >= 0) {
            int b = bv[j];
            int ex = (b > 0) ? lofs[b - 1] : 0;
            int p = ex + atomicAdd(&lcur[b], 1);
            stage[p] = pv[j];
            sbid[p] = (unsigned short)b;
        }
    }
    __syncthreads();
    for (int p = tid; p < nval; p += 1024) {
        int b = sbid[p];
        int ex = (b > 0) ? lofs[b - 1] : 0;
        int dst = lhist[b] + (p - ex);
        if (dst < CAP)
            bucketed[(long long)b * CAP + dst] = stage[p];
    }
}

// ---- fallback for nbuk > NBUK_MAX ----
__global__ void k_bucket_fb(const void* eidx, const int* f64, int E,
                            int* gcur, unsigned* bucketed) {
    int e = blockIdx.x * blockDim.x + threadIdx.x;
    if (e >= E) return;
    int is64 = *f64;
    int r = ld_idx(eidx, e, is64);
    int c = ld_idx(eidx, (long long)E + e, is64);
    int b = c >> BSH;
    int pos = atomicAdd(&gcur[b], 1);
    if (pos < CAP)
        bucketed[(long long)b * CAP + pos] =
            (unsigned)r | ((unsigned)(c & (BNODES - 1)) << 20);
}

// ---- scan per-bucket totals -> bucket edge offsets (+ psum/pcnt zeroing) ----
__global__ __launch_bounds__(512) void k_bscan(const int* __restrict__ gcur,
                                               int* __restrict__ gofs, int nbuk,
                                               int* rowptr, int N,
                                               float* psum, float* pcnt) {
    int tid = threadIdx.x;
    for (int t = tid; t < NG * HID; t += 512) psum[t] = 0.f;
    for (int t = tid; t < NG; t += 512) pcnt[t] = 0.f;
    __shared__ int tot[512];
    int chunk = (nbuk + 511) / 512;
    int st = tid * chunk, en = min(st + chunk, nbuk);
    int s = 0;
    for (int i = st; i < en; ++i) s += min(gcur[i], CAP);
    tot[tid] = s;
    __syncthreads();
    for (int off = 1; off < 512; off <<= 1) {
        int a = (tid >= off) ? tot[tid - off] : 0;
        __syncthreads();
        tot[tid] += a;
        __syncthreads();
    }
    int run = tot[tid] - s;
    for (int i = st; i < en; ++i) { gofs[i] = run; run += min(gcur[i], CAP); }
    if (tid == 511) rowptr[N] = tot[511];
}

// ---- pass 2: per-bucket local counting sort -> rowptr, dinv, csr_src ----
__global__ __launch_bounds__(256) void k_bfill(const int* __restrict__ gcur,
                                               const int* __restrict__ gofs,
                                               const unsigned* __restrict__ bucketed,
                                               int* __restrict__ rowptr,
                                               float* __restrict__ dinv,
                                               int* __restrict__ csr_src, int N) {
    __shared__ int lhist[BNODES], lrp[BNODES], lcur[BNODES];
    __shared__ int stage[CAP];
    int b = blockIdx.x;
    int cnt = min(gcur[b], CAP);
    int base = gofs[b];
    int nb0 = b << BSH;
    int tid = threadIdx.x;
    const unsigned* bk = bucketed + (long long)b * CAP;
    if (tid < BNODES) { lhist[tid] = 0; lcur[tid] = 0; }
    __syncthreads();
    for (int t = tid; t < cnt; t += 256) atomicAdd(&lhist[bk[t] >> 20], 1);
    __syncthreads();
    if (tid < BNODES) lrp[tid] = lhist[tid];
    __syncthreads();
    for (int off = 1; off < BNODES; off <<= 1) {
        int a = (tid < BNODES && tid >= off) ? lrp[tid - off] : 0;
        __syncthreads();
        if (tid < BNODES) lrp[tid] += a;
        __syncthreads();
    }
    if (tid < BNODES) {
        int ex = lrp[tid] - lhist[tid];
        lrp[tid] = ex;
        int node = nb0 + tid;
        if (node < N) {
            rowptr[node] = base + ex;
            dinv[node] = rsqrtf((float)lhist[tid] + 1.0f);
        }
    }
    __syncthreads();
    for (int t = tid; t < cnt; t += 256) {
        unsigned v = bk[t];
        int lc = v >> 20;
        int q = atomicAdd(&lcur[lc], 1);
        stage[lrp[lc] + q] = (int)(v & 0xFFFFFu);
    }
    __syncthreads();
    for (int t = tid; t < cnt; t += 256) csr_src[base + t] = stage[t];
}

// ---- lin1 (MFMA): h0 = relu(x@w1+b1) f16; hs0 = h0*dinv f16 ----
constexpr int LNB = 64;
__global__ __launch_bounds__(256) void k_lin1(const float* __restrict__ x,
                                              const float* __restrict__ w1,
                                              const float* __restrict__ b1,
                                              const float* __restrict__ dinv,
                                              unsigned short* __restrict__ h0,
                                              unsigned short* __restrict__ hs0, int N) {
    __shared__ unsigned short xs[LNB][IN_F];
    __shared__ unsigned short wt[HID][IN_F];
    int tid = threadIdx.x;
    int l = tid & 63, wv = tid >> 6;
    int nb0 = blockIdx.x * LNB;

    for (int t = tid; t < (IN_F * HID / 4); t += 256) {
        int k = t >> 4;
        int n0 = (t & 15) * 4;
        float4 v = *(const float4*)&w1[k * HID + n0];
        int kc = k >> 3, ke = k & 7;
        wt[n0 + 0][((kc ^ ((n0 + 0) & 15)) * 8) + ke] = __half_as_ushort(__float2half(v.x));
        wt[n0 + 1][((kc ^ ((n0 + 1) & 15)) * 8) + ke] = __half_as_ushort(__float2half(v.y));
        wt[n0 + 2][((kc ^ ((n0 + 2) & 15)) * 8) + ke] = __half_as_ushort(__float2half(v.z));
        wt[n0 + 3][((kc ^ ((n0 + 3) & 15)) * 8) + ke] = __half_as_ushort(__float2half(v.w));
    }
    for (int t = tid; t < LNB * (IN_F / 8); t += 256) {
        int row = t >> 4, kc = t & 15;
        int gn = nb0 + row;
        float4 va = make_float4(0.f, 0.f, 0.f, 0.f), vb = va;
        if (gn < N) {
            va = ((const float4*)x)[(long long)gn * 32 + kc * 2];
            vb = ((const float4*)x)[(long long)gn * 32 + kc * 2 + 1];
        }
        __attribute__((aligned(16))) unsigned short t8[8];
        t8[0] = __half_as_ushort(__float2half(va.x));
        t8[1] = __half_as_ushort(__float2half(va.y));
        t8[2] = __half_as_ushort(__float2half(va.z));
        t8[3] = __half_as_ushort(__float2half(va.w));
        t8[4] = __half_as_ushort(__float2half(vb.x));
        t8[5] = __half_as_ushort(__float2half(vb.y));
        t8[6] = __half_as_ushort(__float2half(vb.z));
        t8[7] = __half_as_ushort(__float2half(vb.w));
        int slot = kc ^ (row & 15);
        *(uint4*)&xs[row][slot * 8] = *(uint4*)t8;
    }
    __syncthreads();

    int i16 = l & 15, hk = l >> 4;
    f32x4 acc0 = {0.f,0.f,0.f,0.f}, acc1 = acc0, acc2 = acc0, acc3 = acc0;
    #pragma unroll
    for (int kc4 = 0; kc4 < 4; ++kc4) {
        int kc = kc4 * 4 + hk;
        int arow = wv * 16 + i16;
        half8 av = *(half8*)&xs[arow][(kc ^ (arow & 15)) * 8];
        half8 b0 = *(half8*)&wt[ 0 + i16][(kc ^ (( 0 + i16) & 15)) * 8];
        half8 b1v = *(half8*)&wt[16 + i16][(kc ^ ((16 + i16) & 15)) * 8];
        half8 b2v = *(half8*)&wt[32 + i16][(kc ^ ((32 + i16) & 15)) * 8];
        half8 b3v = *(half8*)&wt[48 + i16][(kc ^ ((48 + i16) & 15)) * 8];
        acc0 = __builtin_amdgcn_mfma_f32_16x16x32_f16(av, b0,  acc0, 0, 0, 0);
        acc1 = __builtin_amdgcn_mfma_f32_16x16x32_f16(av, b1v, acc1, 0, 0, 0);
        acc2 = __builtin_amdgcn_mfma_f32_16x16x32_f16(av, b2v, acc2, 0, 0, 0);
        acc3 = __builtin_amdgcn_mfma_f32_16x16x32_f16(av, b3v, acc3, 0, 0, 0);
    }
    #pragma unroll
    for (int r = 0; r < 4; ++r) {
        int gn = nb0 + wv * 16 + hk * 4 + r;
        if (gn >= N) continue;
        float di = dinv[gn];
        float vr[4] = {acc0[r], acc1[r], acc2[r], acc3[r]};
        #pragma unroll
        for (int ct = 0; ct < 4; ++ct) {
            int col = ct * 16 + i16;
            float v = fmaxf(vr[ct] + b1[col], 0.f);
            h0 [(long long)gn * HID + col] = __half_as_ushort(__float2half(v));
            hs0[(long long)gn * HID + col] = __half_as_ushort(__float2half(v * di));
        }
    }
}

// ---- fused GCN2 layer v8: f16 W^T staging + 8-deep gather + MFMA ----
__global__ __launch_bounds__(256) void k_layer(const int* __restrict__ rowptr,
                                               const int* __restrict__ csr_src,
                                               const float* __restrict__ dinv,
                                               const unsigned short* __restrict__ hs_in,
                                               const unsigned short* __restrict__ h0,
                                               const unsigned short* __restrict__ w16, // [n][k] f16
                                               float beta, int scale_out,
                                               unsigned short* __restrict__ h_out, int N) {
    __shared__ unsigned short s_lds[16][HID];
    __shared__ unsigned short wt_lds[HID][HID];
    __shared__ int ldsidx[EMAX];
    __shared__ int lrowp[17];
    int tid = threadIdx.x;
    int l = tid & 63, wv = tid >> 6;
    int nb = blockIdx.x * 16;

    if (tid < 17) lrowp[tid] = rowptr[min(nb + tid, N)];
    // stage W^T: 512 uint4 total, 2 per thread (coalesced load, swizzled store)
    #pragma unroll
    for (int uu = 0; uu < 2; ++uu) {
        int u = tid * 2 + uu;
        int n = u >> 3, kb = u & 7;
        uint4 v = ((const uint4*)w16)[u];
        *(uint4*)&wt_lds[n][(kb ^ (n & 7)) * 8] = v;
    }
    __syncthreads();

    int eblk0 = lrowp[0];
    int ecnt = lrowp[16] - eblk0;
    bool use_lds = (ecnt <= EMAX);
    if (use_lds)
        for (int t = tid; t < ecnt; t += 256) ldsidx[t] = csr_src[eblk0 + t];
    __syncthreads();

    const uint4* hin4 = (const uint4*)hs_in;
    const uint4* h04  = (const uint4*)h0;
    int j = l >> 4, q = (l >> 3) & 1, m = l & 7;
    int row = wv * 4 + j;
    int node = nb + row;
    int e0 = lrowp[row], e1 = lrowp[row + 1];

    __half2 a[4] = {__half2(0.f, 0.f), __half2(0.f, 0.f),
                    __half2(0.f, 0.f), __half2(0.f, 0.f)};
    __half2 b[4] = {__half2(0.f, 0.f), __half2(0.f, 0.f),
                    __half2(0.f, 0.f), __half2(0.f, 0.f)};
    int e = e0 + q;
    if (use_lds) {
        const int* lx = ldsidx - eblk0;
        // 8-deep: e, e+2, ..., e+14 in flight
        for (; e + 14 < e1; e += 16) {
            int r0 = lx[e],      r1 = lx[e + 2],  r2 = lx[e + 4],  r3 = lx[e + 6];
            int r4 = lx[e + 8],  r5 = lx[e + 10], r6 = lx[e + 12], r7 = lx[e + 14];
            uint4 v0 = hin4[(long long)r0 * 8 + m];
            uint4 v1 = hin4[(long long)r1 * 8 + m];
            uint4 v2 = hin4[(long long)r2 * 8 + m];
            uint4 v3 = hin4[(long long)r3 * 8 + m];
            uint4 v4 = hin4[(long long)r4 * 8 + m];
            uint4 v5 = hin4[(long long)r5 * 8 + m];
            uint4 v6 = hin4[(long long)r6 * 8 + m];
            uint4 v7 = hin4[(long long)r7 * 8 + m];
            const __half2 *p0 = (const __half2*)&v0, *p1 = (const __half2*)&v1;
            const __half2 *p2 = (const __half2*)&v2, *p3 = (const __half2*)&v3;
            const __half2 *p4 = (const __half2*)&v4, *p5 = (const __half2*)&v5;
            const __half2 *p6 = (const __half2*)&v6, *p7 = (const __half2*)&v7;
            #pragma unroll
            for (int jj = 0; jj < 4; ++jj) {
                a[jj] = __hadd2(a[jj], p0[jj]);
                b[jj] = __hadd2(b[jj], p1[jj]);
                a[jj] = __hadd2(a[jj], p2[jj]);
                b[jj] = __hadd2(b[jj], p3[jj]);
            }
            #pragma unroll
            for (int jj = 0; jj < 4; ++jj) {
                a[jj] = __hadd2(a[jj], p4[jj]);
                b[jj] = __hadd2(b[jj], p5[jj]);
                a[jj] = __hadd2(a[jj], p6[jj]);
                b[jj] = __hadd2(b[jj], p7[jj]);
            }
        }
        // 4-deep middle tail
        for (; e + 6 < e1; e += 8) {
            int r0 = lx[e], r1 = lx[e + 2], r2 = lx[e + 4], r3 = lx[e + 6];
            uint4 v0 = hin4[(long long)r0 * 8 + m];
            uint4 v1 = hin4[(long long)r1 * 8 + m];
            uint4 v2 = hin4[(long long)r2 * 8 + m];
            uint4 v3 = hin4[(long long)r3 * 8 + m];
            const __half2 *p0 = (const __half2*)&v0, *p1 = (const __half2*)&v1;
            const __half2 *p2 = (const __half2*)&v2, *p3 = (const __half2*)&v3;
            #pragma unroll
            for (int jj = 0; jj < 4; ++jj) {
                a[jj] = __hadd2(a[jj], p0[jj]);
                b[jj] = __hadd2(b[jj], p1[jj]);
                a[jj] = __hadd2(a[jj], p2[jj]);
                b[jj] = __hadd2(b[jj], p3[jj]);
            }
        }
        for (; e < e1; e += 2) {
            uint4 v = hin4[(long long)lx[e] * 8 + m];
            const __half2* p = (const __half2*)&v;
            #pragma unroll
            for (int jj = 0; jj < 4; ++jj) a[jj] = __hadd2(a[jj], p[jj]);
        }
    } else {
        for (; e + 6 < e1; e += 8) {
            int r0 = csr_src[e], r1 = csr_src[e + 2];
            int r2 = csr_src[e + 4], r3 = csr_src[e + 6];
            uint4 v0 = hin4[(long long)r0 * 8 + m];
            uint4 v1 = hin4[(long long)r1 * 8 + m];
            uint4 v2 = hin4[(long long)r2 * 8 + m];
            uint4 v3 = hin4[(long long)r3 * 8 + m];
            const __half2 *p0 = (const __half2*)&v0, *p1 = (const __half2*)&v1;
            const __half2 *p2 = (const __half2*)&v2, *p3 = (const __half2*)&v3;
            #pragma unroll
            for (int jj = 0; jj < 4; ++jj) {
                a[jj] = __hadd2(a[jj], p0[jj]);
                b[jj] = __hadd2(b[jj], p1[jj]);
                a[jj] = __hadd2(a[jj], p2[jj]);
                b[jj] = __hadd2(b[jj], p3[jj]);
            }
        }
        for (; e < e1; e += 2) {
            uint4 v = hin4[(long long)csr_src[e] * 8 + m];
            const __half2* p = (const __half2*)&v;
            #pragma unroll
            for (int jj = 0; jj < 4; ++jj) a[jj] = __hadd2(a[jj], p[jj]);
        }
    }
    #pragma unroll
    for (int jj = 0; jj < 4; ++jj) a[jj] = __hadd2(a[jj], b[jj]);
    #pragma unroll
    for (int jj = 0; jj < 4; ++jj) {
        unsigned t = __shfl_xor(*(unsigned*)&a[jj], 8, 64);
        a[jj] = __hadd2(a[jj], *(__half2*)&t);
    }
    if (q == 0) {
        if (node < N) {
            float di = dinv[node];
            uint4 hv = hin4[(long long)node * 8 + m];
            uint4 rv = h04 [(long long)node * 8 + m];
            const __half2* hp = (const __half2*)&hv;
            const __half2* rp = (const __half2*)&rv;
            __attribute__((aligned(16))) unsigned short out8[8];
            #pragma unroll
            for (int jj = 0; jj < 4; ++jj) {
                __half2 t = __hadd2(a[jj], hp[jj]);
                float slo = fmaf(0.9f * di, __low2float(t),  0.1f * __low2float(rp[jj]));
                float shi = fmaf(0.9f * di, __high2float(t), 0.1f * __high2float(rp[jj]));
                *(__half2*)&out8[jj * 2] = __floats2half2_rn(slo, shi);
            }
            int slot = m ^ (row & 7);
            *(uint4*)&s_lds[row][slot * 8] = *(uint4*)out8;
        } else {
            int slot = m ^ (row & 7);
            uint4 z = make_uint4(0, 0, 0, 0);
            *(uint4*)&s_lds[row][slot * 8] = z;
        }
    }
    __syncthreads();

    int i16 = l & 15, kc = l >> 4;
    f32x4 acc = {0.f, 0.f, 0.f, 0.f};
    #pragma unroll
    for (int ks = 0; ks < 2; ++ks) {
        int cb = ks * 4 + kc;
        int sa = cb ^ (i16 & 7);
        half8 av = *(half8*)&s_lds[i16][sa * 8];
        int n = wv * 16 + i16;
        int sb = cb ^ (n & 7);
        half8 bv = *(half8*)&wt_lds[n][sb * 8];
        acc = __builtin_amdgcn_mfma_f32_16x16x32_f16(av, bv, acc, 0, 0, 0);
    }
    #pragma unroll
    for (int r = 0; r < 4; ++r) {
        int orow = kc * 4 + r;
        int onode = nb + orow;
        if (onode < N) {
            int colg = wv * 16 + i16;
            int slot = (colg >> 3) ^ (orow & 7);
            __half sh = *(__half*)&s_lds[orow][slot * 8 + (colg & 7)];
            float sv = __half2float(sh);
            float v = fmaxf(sv + beta * (acc[r] - sv), 0.f);
            if (scale_out) v *= dinv[onode];
            __half hv2 = __float2half(v);
            h_out[(long long)onode * HID + colg] = *(unsigned short*)&hv2;
        }
    }
}

// ---- pooling ----
constexpr int POOL_CHUNK = 256;
__global__ __launch_bounds__(256) void k_pool(const unsigned short* __restrict__ h,
                                              const void* batch, const int* f64,
                                              float* psum, float* pcnt, int N) {
    int c = threadIdx.x & 63;
    int g = threadIdx.x >> 6;
    int n0 = blockIdx.x * POOL_CHUNK;
    int nend = min(n0 + POOL_CHUNK, N);
    int is64 = *f64;
    float sum = 0.f;
    int cnt = 0, curb = -1;
    for (int n = n0 + g; n < nend; n += 4) {
        int b = ld_idx(batch, n, is64);
        if (b != curb) {
            if (curb >= 0) {
                atomicAdd(&psum[(long long)curb * HID + c], sum);
                if (c == 0) atomicAdd(&pcnt[curb], (float)cnt);
            }
            curb = b; sum = 0.f; cnt = 0;
        }
        __half hv = *(__half*)&h[(long long)n * HID + c];
        sum += __half2float(hv);
        cnt++;
    }
    if (curb >= 0) {
        atomicAdd(&psum[(long long)curb * HID + c], sum);
        if (c == 0) atomicAdd(&pcnt[curb], (float)cnt);
    }
}

// ---- out[g] = (psum[g]/max(cnt,1)) @ w2 + b2 ----
__global__ void k_out(const float* __restrict__ psum, const float* __restrict__ pcnt,
                      const float* __restrict__ w2, const float* __restrict__ b2,
                      float* __restrict__ out) {
    int g = blockIdx.x;
    int tid = threadIdx.x;
    __shared__ float pr[HID];
    float cnt = fmaxf(pcnt[g], 1.0f);
    pr[tid] = psum[(long long)g * HID + tid] / cnt;
    __syncthreads();
    if (tid < OUT_F) {
        float acc = b2[tid];
        #pragma unroll
        for (int k = 0; k < HID; ++k)
            acc = fmaf(pr[k], w2[k * OUT_F + tid], acc);
        out[g * OUT_F + tid] = acc;
    }
}

static inline size_t align256(size_t x) { return (x + 255) & ~(size_t)255; }

extern "C" void kernel_launch(void* const* d_in, const int* in_sizes, int n_in,
                              void* d_out, int out_size, void* d_ws, size_t ws_size,
                              hipStream_t stream) {
    const float* x     = (const float*)d_in[0];
    const void*  eidx  = d_in[1];
    const void*  batch = d_in[2];
    const float* w1    = (const float*)d_in[3];
    const float* b1    = (const float*)d_in[4];
    const float* convw = (const float*)d_in[5];
    const float* w2    = (const float*)d_in[6];
    const float* b2    = (const float*)d_in[7];
    float* out = (float*)d_out;

    int N = in_sizes[0] / IN_F;
    int E = in_sizes[1] / 2;
    int nbuk = (N + BNODES - 1) >> BSH;

    char* ws = (char*)d_ws;
    float* dinv    = (float*)ws;                ws += align256((size_t)N * 4);
    unsigned short* h0  = (unsigned short*)ws;  ws += align256((size_t)N * HID * 2);
    unsigned short* hs0 = (unsigned short*)ws;  ws += align256((size_t)N * HID * 2);
    unsigned short* hb  = (unsigned short*)ws;  ws += align256((size_t)N * HID * 2);
    float* psum    = (float*)ws;                ws += align256((size_t)NG * HID * 4);
    float* pcnt    = (float*)ws;                ws += align256((size_t)NG * 4);
    int*   rowptr  = (int*)ws;                  ws += align256((size_t)(N + 1) * 4);
    int*   csr_src = (int*)ws;                  ws += align256((size_t)E * 4);
    int*   gcur    = (int*)ws;                  ws += align256((size_t)nbuk * 4);
    int*   gofs    = (int*)ws;                  ws += align256((size_t)(nbuk + 1) * 4);
    unsigned short* w16t = (unsigned short*)ws; ws += align256((size_t)NLAYER * HID * HID * 2);
    unsigned* bucketed = (unsigned*)ws;         ws += align256((size_t)nbuk * CAP * 4);
    int*   flag    = (int*)ws;

    // 1. dtype detect + gcur zeroing + W->f16^T convert
    k_detect<<<1, 256, 0, stream>>>((const unsigned int*)eidx, 4096, flag, gcur, nbuk,
                                    convw, w16t);

    // 2. CSR build: block counting-sort -> scan (+psum zero) -> per-bucket sort
    if (nbuk <= NBUK_MAX)
        k_bucket2<<<(E + EPB - 1) / EPB, 1024, 0, stream>>>(eidx, flag, E, nbuk,
                                                            gcur, bucketed);
    else
        k_bucket_fb<<<(E + 255) / 256, 256, 0, stream>>>(eidx, flag, E, gcur, bucketed);
    k_bscan<<<1, 512, 0, stream>>>(gcur, gofs, nbuk, rowptr, N, psum, pcnt);
    k_bfill<<<nbuk, 256, 0, stream>>>(gcur, gofs, bucketed, rowptr, dinv, csr_src, N);

    // 3. lin1 (MFMA) -> h0 (raw f16) + hs0 (scaled f16)
    k_lin1<<<(N + LNB - 1) / LNB, 256, 0, stream>>>(x, w1, b1, dinv, h0, hs0, N);

    // 4. three fused GCN2 layers: hs0 -> hb -> hs0 -> hb(raw)
    int nlb = (N + 15) / 16;
    float beta0 = logf(0.5f / 1.0f + 1.0f);
    float beta1 = logf(0.5f / 2.0f + 1.0f);
    float beta2 = logf(0.5f / 3.0f + 1.0f);
    k_layer<<<nlb, 256, 0, stream>>>(rowptr, csr_src, dinv, hs0, h0,
                                     w16t + 0 * HID * HID, beta0, 1, hb, N);
    k_layer<<<nlb, 256, 0, stream>>>(rowptr, csr_src, dinv, hb, h0,
                                     w16t + 1 * HID * HID, beta1, 1, hs0, N);
    k_layer<<<nlb, 256, 0, stream>>>(rowptr, csr_src, dinv, hs0, h0,
                                     w16t + 2 * HID * HID, beta2, 0, hb, N);

    // 5. pooling + final linear (raw h is hb)
    k_pool<<<(N + POOL_CHUNK - 1) / POOL_CHUNK, 256, 0, stream>>>(hb, batch, flag,
                                                                  psum, pcnt, N);
    k_out<<<NG, 64, 0, stream>>>(psum, pcnt, w2, b2, out);
}

// Round 15
// 135.594 us; speedup vs baseline: 1.0546x; 1.0546x over previous
//
#include <hip/hip_runtime.h>
#include <hip/hip_fp16.h>
#include <math.h>

constexpr int IN_F = 128;
constexpr int HID  = 64;
constexpr int OUT_F = 10;
constexpr int NG   = 256;
constexpr int BSH  = 7;            // 128 nodes per bucket
constexpr int BNODES = 1 << BSH;
constexpr int CAP  = 3072;         // per-bucket edge capacity (mean ~2046)
constexpr int NBUK_MAX = 1024;     // supports N <= 131072
constexpr int EPB  = 8192;         // edges per bucket-sort block
constexpr int EMAX = 1024;         // LDS edge-stage capacity per layer block
constexpr int NLAYER = 3;

typedef _Float16 half8 __attribute__((ext_vector_type(8)));
typedef float f32x4 __attribute__((ext_vector_type(4)));

// ---- int32/int64 detection + gcur zeroing + W->f16^T pre-convert ----
__global__ void k_detect(const unsigned int* w, int nwords, int* flag,
                         int* gcur, int nbuk,
                         const float* __restrict__ convw,
                         unsigned short* __restrict__ w16t) {
    __shared__ int nz;
    if (threadIdx.x == 0) nz = 0;
    for (int t = threadIdx.x; t < nbuk; t += 256) gcur[t] = 0;
    // w16t[layer][n][k] = (f16) convw[layer][k][n]
    for (int idx = threadIdx.x; idx < NLAYER * HID * HID; idx += 256) {
        int layer = idx >> 12;
        int rem = idx & 4095;
        int n = rem >> 6, k = rem & 63;
        w16t[idx] = __half_as_ushort(__float2half(convw[layer * 4096 + k * HID + n]));
    }
    __syncthreads();
    int seen = 0;
    for (int i = 1 + 2 * (int)threadIdx.x; i < nwords; i += 2 * (int)blockDim.x)
        if (w[i] != 0u) seen = 1;
    if (seen) atomicOr(&nz, 1);
    __syncthreads();
    if (threadIdx.x == 0) *flag = (nz == 0) ? 1 : 0;
}

__device__ __forceinline__ int ld_idx(const void* p, long long i, int is64) {
    return is64 ? (int)((const long long*)p)[i] : ((const int*)p)[i];
}

// ---- pass 1: block-level counting sort into contiguous per-bucket regions ----
__global__ __launch_bounds__(1024) void k_bucket2(const void* eidx, const int* f64,
                                                  int E, int nbuk,
                                                  int* gcur, unsigned* bucketed) {
    __shared__ int lhist[NBUK_MAX];
    __shared__ int lofs[NBUK_MAX];
    __shared__ int lcur[NBUK_MAX];
    __shared__ unsigned stage[EPB];
    __shared__ unsigned short sbid[EPB];
    int tid = threadIdx.x;
    long long base = (long long)blockIdx.x * EPB;
    int nval = (int)min((long long)EPB, (long long)E - base);
    int is64 = *f64;
    lhist[tid] = 0; lcur[tid] = 0;
    __syncthreads();
    unsigned pv[8]; int bv[8];
    #pragma unroll
    for (int j = 0; j < 8; ++j) {
        long long e = base + j * 1024 + tid;
        if (e < E) {
            int r = ld_idx(eidx, e, is64);
            int c = ld_idx(eidx, (long long)E + e, is64);
            int b = c >> BSH;
            pv[j] = (unsigned)r | ((unsigned)(c & (BNODES - 1)) << 20);
            bv[j] = b;
            atomicAdd(&lhist[b], 1);
        } else bv[j] = -1;
    }
    __syncthreads();
    lofs[tid] = lhist[tid];
    __syncthreads();
    for (int off = 1; off < NBUK_MAX; off <<= 1) {
        int v = (tid >= off) ? lofs[tid - off] : 0;
        __syncthreads();
        lofs[tid] += v;
        __syncthreads();
    }
    int cnt = lhist[tid];
    if (tid < nbuk && cnt > 0)
        lhist[tid] = atomicAdd(&gcur[tid], cnt);
    #pragma unroll
    for (int j = 0; j < 8; ++j) {
        if (bv[j] >= 0) {
            int b = bv[j];
            int ex = (b > 0) ? lofs[b - 1] : 0;
            int p = ex + atomicAdd(&lcur[b], 1);
            stage[p] = pv[j];
            sbid[p] = (unsigned short)b;
        }
    }
    __syncthreads();
    for (int p = tid; p < nval; p += 1024) {
        int b = sbid[p];
        int ex = (b > 0) ? lofs[b - 1] : 0;
        int dst = lhist[b] + (p - ex);
        if (dst < CAP)
            bucketed[(long long)b * CAP + dst] = stage[p];
    }
}

// ---- fallback for nbuk > NBUK_MAX ----
__global__ void k_bucket_fb(const void* eidx, const int* f64, int E,
                            int* gcur, unsigned* bucketed) {
    int e = blockIdx.x * blockDim.x + threadIdx.x;
    if (e >= E) return;
    int is64 = *f64;
    int r = ld_idx(eidx, e, is64);
    int c = ld_idx(eidx, (long long)E + e, is64);
    int b = c >> BSH;
    int pos = atomicAdd(&gcur[b], 1);
    if (pos < CAP)
        bucketed[(long long)b * CAP + pos] =
            (unsigned)r | ((unsigned)(c & (BNODES - 1)) << 20);
}

// ---- scan per-bucket totals -> bucket edge offsets (+ psum/pcnt zeroing) ----
__global__ __launch_bounds__(512) void k_bscan(const int* __restrict__ gcur,
                                               int* __restrict__ gofs, int nbuk,
                                               int* rowptr, int N,
                                               float* psum, float* pcnt) {
    int tid = threadIdx.x;
    for (int t = tid; t < NG * HID; t += 512) psum[t] = 0.f;
    for (int t = tid; t < NG; t += 512) pcnt[t] = 0.f;
    __shared__ int tot[512];
    int chunk = (nbuk + 511) / 512;
    int st = tid * chunk, en = min(st + chunk, nbuk);
    int s = 0;
    for (int i = st; i < en; ++i) s += min(gcur[i], CAP);
    tot[tid] = s;
    __syncthreads();
    for (int off = 1; off < 512; off <<= 1) {
        int a = (tid >= off) ? tot[tid - off] : 0;
        __syncthreads();
        tot[tid] += a;
        __syncthreads();
    }
    int run = tot[tid] - s;
    for (int i = st; i < en; ++i) { gofs[i] = run; run += min(gcur[i], CAP); }
    if (tid == 511) rowptr[N] = tot[511];
}

// ---- pass 2: per-bucket local counting sort -> rowptr, dinv, csr_src ----
__global__ __launch_bounds__(256) void k_bfill(const int* __restrict__ gcur,
                                               const int* __restrict__ gofs,
                                               const unsigned* __restrict__ bucketed,
                                               int* __restrict__ rowptr,
                                               float* __restrict__ dinv,
                                               int* __restrict__ csr_src, int N) {
    __shared__ int lhist[BNODES], lrp[BNODES], lcur[BNODES];
    __shared__ int stage[CAP];
    int b = blockIdx.x;
    int cnt = min(gcur[b], CAP);
    int base = gofs[b];
    int nb0 = b << BSH;
    int tid = threadIdx.x;
    const unsigned* bk = bucketed + (long long)b * CAP;
    if (tid < BNODES) { lhist[tid] = 0; lcur[tid] = 0; }
    __syncthreads();
    for (int t = tid; t < cnt; t += 256) atomicAdd(&lhist[bk[t] >> 20], 1);
    __syncthreads();
    if (tid < BNODES) lrp[tid] = lhist[tid];
    __syncthreads();
    for (int off = 1; off < BNODES; off <<= 1) {
        int a = (tid < BNODES && tid >= off) ? lrp[tid - off] : 0;
        __syncthreads();
        if (tid < BNODES) lrp[tid] += a;
        __syncthreads();
    }
    if (tid < BNODES) {
        int ex = lrp[tid] - lhist[tid];
        lrp[tid] = ex;
        int node = nb0 + tid;
        if (node < N) {
            rowptr[node] = base + ex;
            dinv[node] = rsqrtf((float)lhist[tid] + 1.0f);
        }
    }
    __syncthreads();
    for (int t = tid; t < cnt; t += 256) {
        unsigned v = bk[t];
        int lc = v >> 20;
        int q = atomicAdd(&lcur[lc], 1);
        stage[lrp[lc] + q] = (int)(v & 0xFFFFFu);
    }
    __syncthreads();
    for (int t = tid; t < cnt; t += 256) csr_src[base + t] = stage[t];
}

// ---- lin1 (MFMA): h0 = relu(x@w1+b1) f16; hs0 = h0*dinv f16 ----
constexpr int LNB = 64;
__global__ __launch_bounds__(256) void k_lin1(const float* __restrict__ x,
                                              const float* __restrict__ w1,
                                              const float* __restrict__ b1,
                                              const float* __restrict__ dinv,
                                              unsigned short* __restrict__ h0,
                                              unsigned short* __restrict__ hs0, int N) {
    __shared__ unsigned short xs[LNB][IN_F];
    __shared__ unsigned short wt[HID][IN_F];
    int tid = threadIdx.x;
    int l = tid & 63, wv = tid >> 6;
    int nb0 = blockIdx.x * LNB;

    for (int t = tid; t < (IN_F * HID / 4); t += 256) {
        int k = t >> 4;
        int n0 = (t & 15) * 4;
        float4 v = *(const float4*)&w1[k * HID + n0];
        int kc = k >> 3, ke = k & 7;
        wt[n0 + 0][((kc ^ ((n0 + 0) & 15)) * 8) + ke] = __half_as_ushort(__float2half(v.x));
        wt[n0 + 1][((kc ^ ((n0 + 1) & 15)) * 8) + ke] = __half_as_ushort(__float2half(v.y));
        wt[n0 + 2][((kc ^ ((n0 + 2) & 15)) * 8) + ke] = __half_as_ushort(__float2half(v.z));
        wt[n0 + 3][((kc ^ ((n0 + 3) & 15)) * 8) + ke] = __half_as_ushort(__float2half(v.w));
    }
    for (int t = tid; t < LNB * (IN_F / 8); t += 256) {
        int row = t >> 4, kc = t & 15;
        int gn = nb0 + row;
        float4 va = make_float4(0.f, 0.f, 0.f, 0.f), vb = va;
        if (gn < N) {
            va = ((const float4*)x)[(long long)gn * 32 + kc * 2];
            vb = ((const float4*)x)[(long long)gn * 32 + kc * 2 + 1];
        }
        __attribute__((aligned(16))) unsigned short t8[8];
        t8[0] = __half_as_ushort(__float2half(va.x));
        t8[1] = __half_as_ushort(__float2half(va.y));
        t8[2] = __half_as_ushort(__float2half(va.z));
        t8[3] = __half_as_ushort(__float2half(va.w));
        t8[4] = __half_as_ushort(__float2half(vb.x));
        t8[5] = __half_as_ushort(__float2half(vb.y));
        t8[6] = __half_as_ushort(__float2half(vb.z));
        t8[7] = __half_as_ushort(__float2half(vb.w));
        int slot = kc ^ (row & 15);
        *(uint4*)&xs[row][slot * 8] = *(uint4*)t8;
    }
    __syncthreads();

    int i16 = l & 15, hk = l >> 4;
    f32x4 acc0 = {0.f,0.f,0.f,0.f}, acc1 = acc0, acc2 = acc0, acc3 = acc0;
    #pragma unroll
    for (int kc4 = 0; kc4 < 4; ++kc4) {
        int kc = kc4 * 4 + hk;
        int arow = wv * 16 + i16;
        half8 av = *(half8*)&xs[arow][(kc ^ (arow & 15)) * 8];
        half8 b0 = *(half8*)&wt[ 0 + i16][(kc ^ (( 0 + i16) & 15)) * 8];
        half8 b1v = *(half8*)&wt[16 + i16][(kc ^ ((16 + i16) & 15)) * 8];
        half8 b2v = *(half8*)&wt[32 + i16][(kc ^ ((32 + i16) & 15)) * 8];
        half8 b3v = *(half8*)&wt[48 + i16][(kc ^ ((48 + i16) & 15)) * 8];
        acc0 = __builtin_amdgcn_mfma_f32_16x16x32_f16(av, b0,  acc0, 0, 0, 0);
        acc1 = __builtin_amdgcn_mfma_f32_16x16x32_f16(av, b1v, acc1, 0, 0, 0);
        acc2 = __builtin_amdgcn_mfma_f32_16x16x32_f16(av, b2v, acc2, 0, 0, 0);
        acc3 = __builtin_amdgcn_mfma_f32_16x16x32_f16(av, b3v, acc3, 0, 0, 0);
    }
    #pragma unroll
    for (int r = 0; r < 4; ++r) {
        int gn = nb0 + wv * 16 + hk * 4 + r;
        if (gn >= N) continue;
        float di = dinv[gn];
        float vr[4] = {acc0[r], acc1[r], acc2[r], acc3[r]};
        #pragma unroll
        for (int ct = 0; ct < 4; ++ct) {
            int col = ct * 16 + i16;
            float v = fmaxf(vr[ct] + b1[col], 0.f);
            h0 [(long long)gn * HID + col] = __half_as_ushort(__float2half(v));
            hs0[(long long)gn * HID + col] = __half_as_ushort(__float2half(v * di));
        }
    }
}

// ---- fused GCN2 layer v9: f16 W^T staging + 4-node-parallel 4-deep gather + MFMA ----
__global__ __launch_bounds__(256) void k_layer(const int* __restrict__ rowptr,
                                               const int* __restrict__ csr_src,
                                               const float* __restrict__ dinv,
                                               const unsigned short* __restrict__ hs_in,
                                               const unsigned short* __restrict__ h0,
                                               const unsigned short* __restrict__ w16, // [n][k] f16
                                               float beta, int scale_out,
                                               unsigned short* __restrict__ h_out, int N) {
    __shared__ unsigned short s_lds[16][HID];
    __shared__ unsigned short wt_lds[HID][HID];
    __shared__ int ldsidx[EMAX];
    __shared__ int lrowp[17];
    int tid = threadIdx.x;
    int l = tid & 63, wv = tid >> 6;
    int nb = blockIdx.x * 16;

    if (tid < 17) lrowp[tid] = rowptr[min(nb + tid, N)];
    // stage W^T: 512 uint4 total, 2 per thread (coalesced load, swizzled store)
    #pragma unroll
    for (int uu = 0; uu < 2; ++uu) {
        int u = tid * 2 + uu;
        int n = u >> 3, kb = u & 7;
        uint4 v = ((const uint4*)w16)[u];
        *(uint4*)&wt_lds[n][(kb ^ (n & 7)) * 8] = v;
    }
    __syncthreads();

    int eblk0 = lrowp[0];
    int ecnt = lrowp[16] - eblk0;
    bool use_lds = (ecnt <= EMAX);
    if (use_lds)
        for (int t = tid; t < ecnt; t += 256) ldsidx[t] = csr_src[eblk0 + t];
    __syncthreads();

    const uint4* hin4 = (const uint4*)hs_in;
    const uint4* h04  = (const uint4*)h0;
    int j = l >> 4, q = (l >> 3) & 1, m = l & 7;
    int row = wv * 4 + j;
    int node = nb + row;
    int e0 = lrowp[row], e1 = lrowp[row + 1];

    __half2 a[4] = {__half2(0.f, 0.f), __half2(0.f, 0.f),
                    __half2(0.f, 0.f), __half2(0.f, 0.f)};
    __half2 b[4] = {__half2(0.f, 0.f), __half2(0.f, 0.f),
                    __half2(0.f, 0.f), __half2(0.f, 0.f)};
    int e = e0 + q;
    if (use_lds) {
        const int* lx = ldsidx - eblk0;
        for (; e + 6 < e1; e += 8) {           // 4-deep: e, e+2, e+4, e+6 in flight
            int r0 = lx[e], r1 = lx[e + 2], r2 = lx[e + 4], r3 = lx[e + 6];
            uint4 v0 = hin4[(long long)r0 * 8 + m];
            uint4 v1 = hin4[(long long)r1 * 8 + m];
            uint4 v2 = hin4[(long long)r2 * 8 + m];
            uint4 v3 = hin4[(long long)r3 * 8 + m];
            const __half2 *p0 = (const __half2*)&v0, *p1 = (const __half2*)&v1;
            const __half2 *p2 = (const __half2*)&v2, *p3 = (const __half2*)&v3;
            #pragma unroll
            for (int jj = 0; jj < 4; ++jj) {
                a[jj] = __hadd2(a[jj], p0[jj]);
                b[jj] = __hadd2(b[jj], p1[jj]);
            }
            #pragma unroll
            for (int jj = 0; jj < 4; ++jj) {
                a[jj] = __hadd2(a[jj], p2[jj]);
                b[jj] = __hadd2(b[jj], p3[jj]);
            }
        }
        for (; e < e1; e += 2) {
            uint4 v = hin4[(long long)lx[e] * 8 + m];
            const __half2* p = (const __half2*)&v;
            #pragma unroll
            for (int jj = 0; jj < 4; ++jj) a[jj] = __hadd2(a[jj], p[jj]);
        }
    } else {
        for (; e + 6 < e1; e += 8) {
            int r0 = csr_src[e], r1 = csr_src[e + 2];
            int r2 = csr_src[e + 4], r3 = csr_src[e + 6];
            uint4 v0 = hin4[(long long)r0 * 8 + m];
            uint4 v1 = hin4[(long long)r1 * 8 + m];
            uint4 v2 = hin4[(long long)r2 * 8 + m];
            uint4 v3 = hin4[(long long)r3 * 8 + m];
            const __half2 *p0 = (const __half2*)&v0, *p1 = (const __half2*)&v1;
            const __half2 *p2 = (const __half2*)&v2, *p3 = (const __half2*)&v3;
            #pragma unroll
            for (int jj = 0; jj < 4; ++jj) {
                a[jj] = __hadd2(a[jj], p0[jj]);
                b[jj] = __hadd2(b[jj], p1[jj]);
            }
            #pragma unroll
            for (int jj = 0; jj < 4; ++jj) {
                a[jj] = __hadd2(a[jj], p2[jj]);
                b[jj] = __hadd2(b[jj], p3[jj]);
            }
        }
        for (; e < e1; e += 2) {
            uint4 v = hin4[(long long)csr_src[e] * 8 + m];
            const __half2* p = (const __half2*)&v;
            #pragma unroll
            for (int jj = 0; jj < 4; ++jj) a[jj] = __hadd2(a[jj], p[jj]);
        }
    }
    #pragma unroll
    for (int jj = 0; jj < 4; ++jj) a[jj] = __hadd2(a[jj], b[jj]);
    #pragma unroll
    for (int jj = 0; jj < 4; ++jj) {
        unsigned t = __shfl_xor(*(unsigned*)&a[jj], 8, 64);
        a[jj] = __hadd2(a[jj], *(__half2*)&t);
    }
    if (q == 0) {
        if (node < N) {
            float di = dinv[node];
            uint4 hv = hin4[(long long)node * 8 + m];
            uint4 rv = h04 [(long long)node * 8 + m];
            const __half2* hp = (const __half2*)&hv;
            const __half2* rp = (const __half2*)&rv;
            __attribute__((aligned(16))) unsigned short out8[8];
            #pragma unroll
            for (int jj = 0; jj < 4; ++jj) {
                __half2 t = __hadd2(a[jj], hp[jj]);
                float slo = fmaf(0.9f * di, __low2float(t),  0.1f * __low2float(rp[jj]));
                float shi = fmaf(0.9f * di, __high2float(t), 0.1f * __high2float(rp[jj]));
                *(__half2*)&out8[jj * 2] = __floats2half2_rn(slo, shi);
            }
            int slot = m ^ (row & 7);
            *(uint4*)&s_lds[row][slot * 8] = *(uint4*)out8;
        } else {
            int slot = m ^ (row & 7);
            uint4 z = make_uint4(0, 0, 0, 0);
            *(uint4*)&s_lds[row][slot * 8] = z;
        }
    }
    __syncthreads();

    int i16 = l & 15, kc = l >> 4;
    f32x4 acc = {0.f, 0.f, 0.f, 0.f};
    #pragma unroll
    for (int ks = 0; ks < 2; ++ks) {
        int cb = ks * 4 + kc;
        int sa = cb ^ (i16 & 7);
        half8 av = *(half8*)&s_lds[i16][sa * 8];
        int n = wv * 16 + i16;
        int sb = cb ^ (n & 7);
        half8 bv = *(half8*)&wt_lds[n][sb * 8];
        acc = __builtin_amdgcn_mfma_f32_16x16x32_f16(av, bv, acc, 0, 0, 0);
    }
    #pragma unroll
    for (int r = 0; r < 4; ++r) {
        int orow = kc * 4 + r;
        int onode = nb + orow;
        if (onode < N) {
            int colg = wv * 16 + i16;
            int slot = (colg >> 3) ^ (orow & 7);
            __half sh = *(__half*)&s_lds[orow][slot * 8 + (colg & 7)];
            float sv = __half2float(sh);
            float v = fmaxf(sv + beta * (acc[r] - sv), 0.f);
            if (scale_out) v *= dinv[onode];
            __half hv2 = __float2half(v);
            h_out[(long long)onode * HID + colg] = *(unsigned short*)&hv2;
        }
    }
}

// ---- pooling ----
constexpr int POOL_CHUNK = 256;
__global__ __launch_bounds__(256) void k_pool(const unsigned short* __restrict__ h,
                                              const void* batch, const int* f64,
                                              float* psum, float* pcnt, int N) {
    int c = threadIdx.x & 63;
    int g = threadIdx.x >> 6;
    int n0 = blockIdx.x * POOL_CHUNK;
    int nend = min(n0 + POOL_CHUNK, N);
    int is64 = *f64;
    float sum = 0.f;
    int cnt = 0, curb = -1;
    for (int n = n0 + g; n < nend; n += 4) {
        int b = ld_idx(batch, n, is64);
        if (b != curb) {
            if (curb >= 0) {
                atomicAdd(&psum[(long long)curb * HID + c], sum);
                if (c == 0) atomicAdd(&pcnt[curb], (float)cnt);
            }
            curb = b; sum = 0.f; cnt = 0;
        }
        __half hv = *(__half*)&h[(long long)n * HID + c];
        sum += __half2float(hv);
        cnt++;
    }
    if (curb >= 0) {
        atomicAdd(&psum[(long long)curb * HID + c], sum);
        if (c == 0) atomicAdd(&pcnt[curb], (float)cnt);
    }
}

// ---- out[g] = (psum[g]/max(cnt,1)) @ w2 + b2 ----
__global__ void k_out(const float* __restrict__ psum, const float* __restrict__ pcnt,
                      const float* __restrict__ w2, const float* __restrict__ b2,
                      float* __restrict__ out) {
    int g = blockIdx.x;
    int tid = threadIdx.x;
    __shared__ float pr[HID];
    float cnt = fmaxf(pcnt[g], 1.0f);
    pr[tid] = psum[(long long)g * HID + tid] / cnt;
    __syncthreads();
    if (tid < OUT_F) {
        float acc = b2[tid];
        #pragma unroll
        for (int k = 0; k < HID; ++k)
            acc = fmaf(pr[k], w2[k * OUT_F + tid], acc);
        out[g * OUT_F + tid] = acc;
    }
}

static inline size_t align256(size_t x) { return (x + 255) & ~(size_t)255; }

extern "C" void kernel_launch(void* const* d_in, const int* in_sizes, int n_in,
                              void* d_out, int out_size, void* d_ws, size_t ws_size,
                              hipStream_t stream) {
    const float* x     = (const float*)d_in[0];
    const void*  eidx  = d_in[1];
    const void*  batch = d_in[2];
    const float* w1    = (const float*)d_in[3];
    const float* b1    = (const float*)d_in[4];
    const float* convw = (const float*)d_in[5];
    const float* w2    = (const float*)d_in[6];
    const float* b2    = (const float*)d_in[7];
    float* out = (float*)d_out;

    int N = in_sizes[0] / IN_F;
    int E = in_sizes[1] / 2;
    int nbuk = (N + BNODES - 1) >> BSH;

    char* ws = (char*)d_ws;
    float* dinv    = (float*)ws;                ws += align256((size_t)N * 4);
    unsigned short* h0  = (unsigned short*)ws;  ws += align256((size_t)N * HID * 2);
    unsigned short* hs0 = (unsigned short*)ws;  ws += align256((size_t)N * HID * 2);
    unsigned short* hb  = (unsigned short*)ws;  ws += align256((size_t)N * HID * 2);
    float* psum    = (float*)ws;                ws += align256((size_t)NG * HID * 4);
    float* pcnt    = (float*)ws;                ws += align256((size_t)NG * 4);
    int*   rowptr  = (int*)ws;                  ws += align256((size_t)(N + 1) * 4);
    int*   csr_src = (int*)ws;                  ws += align256((size_t)E * 4);
    int*   gcur    = (int*)ws;                  ws += align256((size_t)nbuk * 4);
    int*   gofs    = (int*)ws;                  ws += align256((size_t)(nbuk + 1) * 4);
    unsigned short* w16t = (unsigned short*)ws; ws += align256((size_t)NLAYER * HID * HID * 2);
    unsigned* bucketed = (unsigned*)ws;         ws += align256((size_t)nbuk * CAP * 4);
    int*   flag    = (int*)ws;

    // 1. dtype detect + gcur zeroing + W->f16^T convert
    k_detect<<<1, 256, 0, stream>>>((const unsigned int*)eidx, 4096, flag, gcur, nbuk,
                                    convw, w16t);

    // 2. CSR build: block counting-sort -> scan (+psum zero) -> per-bucket sort
    if (nbuk <= NBUK_MAX)
        k_bucket2<<<(E + EPB - 1) / EPB, 1024, 0, stream>>>(eidx, flag, E, nbuk,
                                                            gcur, bucketed);
    else
        k_bucket_fb<<<(E + 255) / 256, 256, 0, stream>>>(eidx, flag, E, gcur, bucketed);
    k_bscan<<<1, 512, 0, stream>>>(gcur, gofs, nbuk, rowptr, N, psum, pcnt);
    k_bfill<<<nbuk, 256, 0, stream>>>(gcur, gofs, bucketed, rowptr, dinv, csr_src, N);

    // 3. lin1 (MFMA) -> h0 (raw f16) + hs0 (scaled f16)
    k_lin1<<<(N + LNB - 1) / LNB, 256, 0, stream>>>(x, w1, b1, dinv, h0, hs0, N);

    // 4. three fused GCN2 layers: hs0 -> hb -> hs0 -> hb(raw)
    int nlb = (N + 15) / 16;
    float beta0 = logf(0.5f / 1.0f + 1.0f);
    float beta1 = logf(0.5f / 2.0f + 1.0f);
    float beta2 = logf(0.5f / 3.0f + 1.0f);
    k_layer<<<nlb, 256, 0, stream>>>(rowptr, csr_src, dinv, hs0, h0,
                                     w16t + 0 * HID * HID, beta0, 1, hb, N);
    k_layer<<<nlb, 256, 0, stream>>>(rowptr, csr_src, dinv, hb, h0,
                                     w16t + 1 * HID * HID, beta1, 1, hs0, N);
    k_layer<<<nlb, 256, 0, stream>>>(rowptr, csr_src, dinv, hs0, h0,
                                     w16t + 2 * HID * HID, beta2, 0, hb, N);

    // 5. pooling + final linear (raw h is hb)
    k_pool<<<(N + POOL_CHUNK - 1) / POOL_CHUNK, 256, 0, stream>>>(hb, batch, flag,
                                                                  psum, pcnt, N);
    k_out<<<NG, 64, 0, stream>>>(psum, pcnt, w2, b2, out);
}

// Round 16
// 134.863 us; speedup vs baseline: 1.0603x; 1.0054x over previous
//
#include <hip/hip_runtime.h>
#include <hip/hip_fp16.h>
#include <math.h>

constexpr int IN_F = 128;
constexpr int HID  = 64;
constexpr int OUT_F = 10;
constexpr int NG   = 256;
constexpr int BSH  = 7;            // 128 nodes per bucket
constexpr int BNODES = 1 << BSH;
constexpr int CAP  = 3072;         // per-bucket edge capacity (mean ~2046)
constexpr int NBUK_MAX = 1024;     // supports N <= 131072
constexpr int EPB  = 8192;         // edges per bucket-sort block
constexpr int EMAX = 1024;         // LDS edge-stage capacity per layer block
constexpr int NLAYER = 3;

typedef _Float16 half8 __attribute__((ext_vector_type(8)));
typedef float f32x4 __attribute__((ext_vector_type(4)));

// ---- detect dtype + zero gcur/psum/pcnt/done + W->f16^T pre-convert ----
__global__ void k_detect(const unsigned int* w, int nwords, int* flag,
                         int* gcur, int nbuk,
                         const float* __restrict__ convw,
                         unsigned short* __restrict__ w16t,
                         float* psum, float* pcnt, int* done) {
    __shared__ int nz;
    if (threadIdx.x == 0) { nz = 0; *done = 0; }
    for (int t = threadIdx.x; t < nbuk; t += 256) gcur[t] = 0;
    for (int t = threadIdx.x; t < NG * HID; t += 256) psum[t] = 0.f;
    for (int t = threadIdx.x; t < NG; t += 256) pcnt[t] = 0.f;
    // w16t[layer][n][k] = (f16) convw[layer][k][n]
    for (int idx = threadIdx.x; idx < NLAYER * HID * HID; idx += 256) {
        int layer = idx >> 12;
        int rem = idx & 4095;
        int n = rem >> 6, k = rem & 63;
        w16t[idx] = __half_as_ushort(__float2half(convw[layer * 4096 + k * HID + n]));
    }
    __syncthreads();
    int seen = 0;
    for (int i = 1 + 2 * (int)threadIdx.x; i < nwords; i += 2 * (int)blockDim.x)
        if (w[i] != 0u) seen = 1;
    if (seen) atomicOr(&nz, 1);
    __syncthreads();
    if (threadIdx.x == 0) *flag = (nz == 0) ? 1 : 0;
}

__device__ __forceinline__ int ld_idx(const void* p, long long i, int is64) {
    return is64 ? (int)((const long long*)p)[i] : ((const int*)p)[i];
}

// ---- pass 1: block-level counting sort into contiguous per-bucket regions ----
__global__ __launch_bounds__(1024) void k_bucket2(const void* eidx, const int* f64,
                                                  int E, int nbuk,
                                                  int* gcur, unsigned* bucketed) {
    __shared__ int lhist[NBUK_MAX];
    __shared__ int lofs[NBUK_MAX];
    __shared__ int lcur[NBUK_MAX];
    __shared__ unsigned stage[EPB];
    __shared__ unsigned short sbid[EPB];
    int tid = threadIdx.x;
    long long base = (long long)blockIdx.x * EPB;
    int nval = (int)min((long long)EPB, (long long)E - base);
    int is64 = *f64;
    lhist[tid] = 0; lcur[tid] = 0;
    __syncthreads();
    unsigned pv[8]; int bv[8];
    #pragma unroll
    for (int j = 0; j < 8; ++j) {
        long long e = base + j * 1024 + tid;
        if (e < E) {
            int r = ld_idx(eidx, e, is64);
            int c = ld_idx(eidx, (long long)E + e, is64);
            int b = c >> BSH;
            pv[j] = (unsigned)r | ((unsigned)(c & (BNODES - 1)) << 20);
            bv[j] = b;
            atomicAdd(&lhist[b], 1);
        } else bv[j] = -1;
    }
    __syncthreads();
    lofs[tid] = lhist[tid];
    __syncthreads();
    for (int off = 1; off < NBUK_MAX; off <<= 1) {
        int v = (tid >= off) ? lofs[tid - off] : 0;
        __syncthreads();
        lofs[tid] += v;
        __syncthreads();
    }
    int cnt = lhist[tid];
    if (tid < nbuk && cnt > 0)
        lhist[tid] = atomicAdd(&gcur[tid], cnt);
    #pragma unroll
    for (int j = 0; j < 8; ++j) {
        if (bv[j] >= 0) {
            int b = bv[j];
            int ex = (b > 0) ? lofs[b - 1] : 0;
            int p = ex + atomicAdd(&lcur[b], 1);
            stage[p] = pv[j];
            sbid[p] = (unsigned short)b;
        }
    }
    __syncthreads();
    for (int p = tid; p < nval; p += 1024) {
        int b = sbid[p];
        int ex = (b > 0) ? lofs[b - 1] : 0;
        int dst = lhist[b] + (p - ex);
        if (dst < CAP)
            bucketed[(long long)b * CAP + dst] = stage[p];
    }
}

// ---- fallback for nbuk > NBUK_MAX ----
__global__ void k_bucket_fb(const void* eidx, const int* f64, int E,
                            int* gcur, unsigned* bucketed) {
    int e = blockIdx.x * blockDim.x + threadIdx.x;
    if (e >= E) return;
    int is64 = *f64;
    int r = ld_idx(eidx, e, is64);
    int c = ld_idx(eidx, (long long)E + e, is64);
    int b = c >> BSH;
    int pos = atomicAdd(&gcur[b], 1);
    if (pos < CAP)
        bucketed[(long long)b * CAP + pos] =
            (unsigned)r | ((unsigned)(c & (BNODES - 1)) << 20);
}

// ---- pass 2: per-bucket counting sort; computes OWN prefix (no bscan) ----
__global__ __launch_bounds__(256) void k_bfill(const int* __restrict__ gcur,
                                               const unsigned* __restrict__ bucketed,
                                               int* __restrict__ rowptr,
                                               float* __restrict__ dinv,
                                               int* __restrict__ csr_src,
                                               int N, int nbuk) {
    __shared__ int lhist[BNODES], lrp[BNODES], lcur[BNODES];
    __shared__ int stage[CAP];
    int b = blockIdx.x;
    int cnt = min(gcur[b], CAP);
    int nb0 = b << BSH;
    int tid = threadIdx.x;
    const unsigned* bk = bucketed + (long long)b * CAP;

    // own exclusive prefix over buckets < b (reuse `stage` as scratch)
    int s = 0;
    for (int i = tid; i < b; i += 256) s += min(gcur[i], CAP);
    stage[tid] = s;
    __syncthreads();
    for (int off = 128; off > 0; off >>= 1) {
        if (tid < off) stage[tid] += stage[tid + off];
        __syncthreads();
    }
    int base = stage[0];
    __syncthreads();
    if (b == nbuk - 1 && tid == 0) rowptr[N] = base + cnt;

    if (tid < BNODES) { lhist[tid] = 0; lcur[tid] = 0; }
    __syncthreads();
    for (int t = tid; t < cnt; t += 256) atomicAdd(&lhist[bk[t] >> 20], 1);
    __syncthreads();
    if (tid < BNODES) lrp[tid] = lhist[tid];
    __syncthreads();
    for (int off = 1; off < BNODES; off <<= 1) {
        int a = (tid < BNODES && tid >= off) ? lrp[tid - off] : 0;
        __syncthreads();
        if (tid < BNODES) lrp[tid] += a;
        __syncthreads();
    }
    if (tid < BNODES) {
        int ex = lrp[tid] - lhist[tid];
        lrp[tid] = ex;
        int node = nb0 + tid;
        if (node < N) {
            rowptr[node] = base + ex;
            dinv[node] = rsqrtf((float)lhist[tid] + 1.0f);
        }
    }
    __syncthreads();
    for (int t = tid; t < cnt; t += 256) {
        unsigned v = bk[t];
        int lc = v >> 20;
        int q = atomicAdd(&lcur[lc], 1);
        stage[lrp[lc] + q] = (int)(v & 0xFFFFFu);
    }
    __syncthreads();
    for (int t = tid; t < cnt; t += 256) csr_src[base + t] = stage[t];
}

// ---- lin1 (MFMA): h0 = relu(x@w1+b1) f16; hs0 = h0*dinv f16 ----
constexpr int LNB = 64;
__global__ __launch_bounds__(256) void k_lin1(const float* __restrict__ x,
                                              const float* __restrict__ w1,
                                              const float* __restrict__ b1,
                                              const float* __restrict__ dinv,
                                              unsigned short* __restrict__ h0,
                                              unsigned short* __restrict__ hs0, int N) {
    __shared__ unsigned short xs[LNB][IN_F];
    __shared__ unsigned short wt[HID][IN_F];
    int tid = threadIdx.x;
    int l = tid & 63, wv = tid >> 6;
    int nb0 = blockIdx.x * LNB;

    for (int t = tid; t < (IN_F * HID / 4); t += 256) {
        int k = t >> 4;
        int n0 = (t & 15) * 4;
        float4 v = *(const float4*)&w1[k * HID + n0];
        int kc = k >> 3, ke = k & 7;
        wt[n0 + 0][((kc ^ ((n0 + 0) & 15)) * 8) + ke] = __half_as_ushort(__float2half(v.x));
        wt[n0 + 1][((kc ^ ((n0 + 1) & 15)) * 8) + ke] = __half_as_ushort(__float2half(v.y));
        wt[n0 + 2][((kc ^ ((n0 + 2) & 15)) * 8) + ke] = __half_as_ushort(__float2half(v.z));
        wt[n0 + 3][((kc ^ ((n0 + 3) & 15)) * 8) + ke] = __half_as_ushort(__float2half(v.w));
    }
    for (int t = tid; t < LNB * (IN_F / 8); t += 256) {
        int row = t >> 4, kc = t & 15;
        int gn = nb0 + row;
        float4 va = make_float4(0.f, 0.f, 0.f, 0.f), vb = va;
        if (gn < N) {
            va = ((const float4*)x)[(long long)gn * 32 + kc * 2];
            vb = ((const float4*)x)[(long long)gn * 32 + kc * 2 + 1];
        }
        __attribute__((aligned(16))) unsigned short t8[8];
        t8[0] = __half_as_ushort(__float2half(va.x));
        t8[1] = __half_as_ushort(__float2half(va.y));
        t8[2] = __half_as_ushort(__float2half(va.z));
        t8[3] = __half_as_ushort(__float2half(va.w));
        t8[4] = __half_as_ushort(__float2half(vb.x));
        t8[5] = __half_as_ushort(__float2half(vb.y));
        t8[6] = __half_as_ushort(__float2half(vb.z));
        t8[7] = __half_as_ushort(__float2half(vb.w));
        int slot = kc ^ (row & 15);
        *(uint4*)&xs[row][slot * 8] = *(uint4*)t8;
    }
    __syncthreads();

    int i16 = l & 15, hk = l >> 4;
    f32x4 acc0 = {0.f,0.f,0.f,0.f}, acc1 = acc0, acc2 = acc0, acc3 = acc0;
    #pragma unroll
    for (int kc4 = 0; kc4 < 4; ++kc4) {
        int kc = kc4 * 4 + hk;
        int arow = wv * 16 + i16;
        half8 av = *(half8*)&xs[arow][(kc ^ (arow & 15)) * 8];
        half8 b0 = *(half8*)&wt[ 0 + i16][(kc ^ (( 0 + i16) & 15)) * 8];
        half8 b1v = *(half8*)&wt[16 + i16][(kc ^ ((16 + i16) & 15)) * 8];
        half8 b2v = *(half8*)&wt[32 + i16][(kc ^ ((32 + i16) & 15)) * 8];
        half8 b3v = *(half8*)&wt[48 + i16][(kc ^ ((48 + i16) & 15)) * 8];
        acc0 = __builtin_amdgcn_mfma_f32_16x16x32_f16(av, b0,  acc0, 0, 0, 0);
        acc1 = __builtin_amdgcn_mfma_f32_16x16x32_f16(av, b1v, acc1, 0, 0, 0);
        acc2 = __builtin_amdgcn_mfma_f32_16x16x32_f16(av, b2v, acc2, 0, 0, 0);
        acc3 = __builtin_amdgcn_mfma_f32_16x16x32_f16(av, b3v, acc3, 0, 0, 0);
    }
    #pragma unroll
    for (int r = 0; r < 4; ++r) {
        int gn = nb0 + wv * 16 + hk * 4 + r;
        if (gn >= N) continue;
        float di = dinv[gn];
        float vr[4] = {acc0[r], acc1[r], acc2[r], acc3[r]};
        #pragma unroll
        for (int ct = 0; ct < 4; ++ct) {
            int col = ct * 16 + i16;
            float v = fmaxf(vr[ct] + b1[col], 0.f);
            h0 [(long long)gn * HID + col] = __half_as_ushort(__float2half(v));
            hs0[(long long)gn * HID + col] = __half_as_ushort(__float2half(v * di));
        }
    }
}

// ---- fused GCN2 layer (round-15 proven structure, unchanged) ----
__global__ __launch_bounds__(256) void k_layer(const int* __restrict__ rowptr,
                                               const int* __restrict__ csr_src,
                                               const float* __restrict__ dinv,
                                               const unsigned short* __restrict__ hs_in,
                                               const unsigned short* __restrict__ h0,
                                               const unsigned short* __restrict__ w16,
                                               float beta, int scale_out,
                                               unsigned short* __restrict__ h_out, int N) {
    __shared__ unsigned short s_lds[16][HID];
    __shared__ unsigned short wt_lds[HID][HID];
    __shared__ int ldsidx[EMAX];
    __shared__ int lrowp[17];
    int tid = threadIdx.x;
    int l = tid & 63, wv = tid >> 6;
    int nb = blockIdx.x * 16;

    if (tid < 17) lrowp[tid] = rowptr[min(nb + tid, N)];
    #pragma unroll
    for (int uu = 0; uu < 2; ++uu) {
        int u = tid * 2 + uu;
        int n = u >> 3, kb = u & 7;
        uint4 v = ((const uint4*)w16)[u];
        *(uint4*)&wt_lds[n][(kb ^ (n & 7)) * 8] = v;
    }
    __syncthreads();

    int eblk0 = lrowp[0];
    int ecnt = lrowp[16] - eblk0;
    bool use_lds = (ecnt <= EMAX);
    if (use_lds)
        for (int t = tid; t < ecnt; t += 256) ldsidx[t] = csr_src[eblk0 + t];
    __syncthreads();

    const uint4* hin4 = (const uint4*)hs_in;
    const uint4* h04  = (const uint4*)h0;
    int j = l >> 4, q = (l >> 3) & 1, m = l & 7;
    int row = wv * 4 + j;
    int node = nb + row;
    int e0 = lrowp[row], e1 = lrowp[row + 1];

    __half2 a[4] = {__half2(0.f, 0.f), __half2(0.f, 0.f),
                    __half2(0.f, 0.f), __half2(0.f, 0.f)};
    __half2 b[4] = {__half2(0.f, 0.f), __half2(0.f, 0.f),
                    __half2(0.f, 0.f), __half2(0.f, 0.f)};
    int e = e0 + q;
    if (use_lds) {
        const int* lx = ldsidx - eblk0;
        for (; e + 6 < e1; e += 8) {
            int r0 = lx[e], r1 = lx[e + 2], r2 = lx[e + 4], r3 = lx[e + 6];
            uint4 v0 = hin4[(long long)r0 * 8 + m];
            uint4 v1 = hin4[(long long)r1 * 8 + m];
            uint4 v2 = hin4[(long long)r2 * 8 + m];
            uint4 v3 = hin4[(long long)r3 * 8 + m];
            const __half2 *p0 = (const __half2*)&v0, *p1 = (const __half2*)&v1;
            const __half2 *p2 = (const __half2*)&v2, *p3 = (const __half2*)&v3;
            #pragma unroll
            for (int jj = 0; jj < 4; ++jj) {
                a[jj] = __hadd2(a[jj], p0[jj]);
                b[jj] = __hadd2(b[jj], p1[jj]);
            }
            #pragma unroll
            for (int jj = 0; jj < 4; ++jj) {
                a[jj] = __hadd2(a[jj], p2[jj]);
                b[jj] = __hadd2(b[jj], p3[jj]);
            }
        }
        for (; e < e1; e += 2) {
            uint4 v = hin4[(long long)lx[e] * 8 + m];
            const __half2* p = (const __half2*)&v;
            #pragma unroll
            for (int jj = 0; jj < 4; ++jj) a[jj] = __hadd2(a[jj], p[jj]);
        }
    } else {
        for (; e + 6 < e1; e += 8) {
            int r0 = csr_src[e], r1 = csr_src[e + 2];
            int r2 = csr_src[e + 4], r3 = csr_src[e + 6];
            uint4 v0 = hin4[(long long)r0 * 8 + m];
            uint4 v1 = hin4[(long long)r1 * 8 + m];
            uint4 v2 = hin4[(long long)r2 * 8 + m];
            uint4 v3 = hin4[(long long)r3 * 8 + m];
            const __half2 *p0 = (const __half2*)&v0, *p1 = (const __half2*)&v1;
            const __half2 *p2 = (const __half2*)&v2, *p3 = (const __half2*)&v3;
            #pragma unroll
            for (int jj = 0; jj < 4; ++jj) {
                a[jj] = __hadd2(a[jj], p0[jj]);
                b[jj] = __hadd2(b[jj], p1[jj]);
            }
            #pragma unroll
            for (int jj = 0; jj < 4; ++jj) {
                a[jj] = __hadd2(a[jj], p2[jj]);
                b[jj] = __hadd2(b[jj], p3[jj]);
            }
        }
        for (; e < e1; e += 2) {
            uint4 v = hin4[(long long)csr_src[e] * 8 + m];
            const __half2* p = (const __half2*)&v;
            #pragma unroll
            for (int jj = 0; jj < 4; ++jj) a[jj] = __hadd2(a[jj], p[jj]);
        }
    }
    #pragma unroll
    for (int jj = 0; jj < 4; ++jj) a[jj] = __hadd2(a[jj], b[jj]);
    #pragma unroll
    for (int jj = 0; jj < 4; ++jj) {
        unsigned t = __shfl_xor(*(unsigned*)&a[jj], 8, 64);
        a[jj] = __hadd2(a[jj], *(__half2*)&t);
    }
    if (q == 0) {
        if (node < N) {
            float di = dinv[node];
            uint4 hv = hin4[(long long)node * 8 + m];
            uint4 rv = h04 [(long long)node * 8 + m];
            const __half2* hp = (const __half2*)&hv;
            const __half2* rp = (const __half2*)&rv;
            __attribute__((aligned(16))) unsigned short out8[8];
            #pragma unroll
            for (int jj = 0; jj < 4; ++jj) {
                __half2 t = __hadd2(a[jj], hp[jj]);
                float slo = fmaf(0.9f * di, __low2float(t),  0.1f * __low2float(rp[jj]));
                float shi = fmaf(0.9f * di, __high2float(t), 0.1f * __high2float(rp[jj]));
                *(__half2*)&out8[jj * 2] = __floats2half2_rn(slo, shi);
            }
            int slot = m ^ (row & 7);
            *(uint4*)&s_lds[row][slot * 8] = *(uint4*)out8;
        } else {
            int slot = m ^ (row & 7);
            uint4 z = make_uint4(0, 0, 0, 0);
            *(uint4*)&s_lds[row][slot * 8] = z;
        }
    }
    __syncthreads();

    int i16 = l & 15, kc = l >> 4;
    f32x4 acc = {0.f, 0.f, 0.f, 0.f};
    #pragma unroll
    for (int ks = 0; ks < 2; ++ks) {
        int cb = ks * 4 + kc;
        int sa = cb ^ (i16 & 7);
        half8 av = *(half8*)&s_lds[i16][sa * 8];
        int n = wv * 16 + i16;
        int sb = cb ^ (n & 7);
        half8 bv = *(half8*)&wt_lds[n][sb * 8];
        acc = __builtin_amdgcn_mfma_f32_16x16x32_f16(av, bv, acc, 0, 0, 0);
    }
    #pragma unroll
    for (int r = 0; r < 4; ++r) {
        int orow = kc * 4 + r;
        int onode = nb + orow;
        if (onode < N) {
            int colg = wv * 16 + i16;
            int slot = (colg >> 3) ^ (orow & 7);
            __half sh = *(__half*)&s_lds[orow][slot * 8 + (colg & 7)];
            float sv = __half2float(sh);
            float v = fmaxf(sv + beta * (acc[r] - sv), 0.f);
            if (scale_out) v *= dinv[onode];
            __half hv2 = __float2half(v);
            h_out[(long long)onode * HID + colg] = *(unsigned short*)&hv2;
        }
    }
}

// ---- pooling (half2-vectorized) + fused final linear via last-block-done ----
constexpr int POOL_CHUNK = 256;
__global__ __launch_bounds__(256) void k_pool(const unsigned short* __restrict__ h,
                                              const void* batch, const int* f64,
                                              float* psum, float* pcnt, int N,
                                              const float* __restrict__ w2,
                                              const float* __restrict__ b2,
                                              float* __restrict__ out,
                                              int* done, int nblocks) {
    __shared__ int islast;
    int tid = threadIdx.x;
    int g = tid >> 5;            // 8 half-wave groups, 1 node each per step
    int lane = tid & 31;         // channel pair index
    int n0 = blockIdx.x * POOL_CHUNK;
    int nend = min(n0 + POOL_CHUNK, N);
    int is64 = *f64;
    const unsigned* h2 = (const unsigned*)h;   // __half2 per 2 channels
    float sx = 0.f, sy = 0.f;
    int cnt = 0, curb = -1;
    for (int n = n0 + g; n < nend; n += 8) {
        int b = ld_idx(batch, n, is64);
        if (b != curb) {
            if (curb >= 0) {
                atomicAdd(&psum[(long long)curb * HID + lane * 2], sx);
                atomicAdd(&psum[(long long)curb * HID + lane * 2 + 1], sy);
                if (lane == 0) atomicAdd(&pcnt[curb], (float)cnt);
            }
            curb = b; sx = 0.f; sy = 0.f; cnt = 0;
        }
        unsigned v = h2[(long long)n * 32 + lane];
        __half2 hv = *(__half2*)&v;
        sx += __low2float(hv);
        sy += __high2float(hv);
        cnt++;
    }
    if (curb >= 0) {
        atomicAdd(&psum[(long long)curb * HID + lane * 2], sx);
        atomicAdd(&psum[(long long)curb * HID + lane * 2 + 1], sy);
        if (lane == 0) atomicAdd(&pcnt[curb], (float)cnt);
    }
    // last-block-done: final linear
    __threadfence();
    __syncthreads();
    if (tid == 0) {
        int v = atomicAdd(done, 1);
        islast = (v == nblocks - 1) ? 1 : 0;
    }
    __syncthreads();
    if (!islast) return;
    __threadfence();
    for (int gg = tid; gg < NG; gg += 256) {
        float c = fmaxf(pcnt[gg], 1.0f);
        float acc[OUT_F];
        #pragma unroll
        for (int o = 0; o < OUT_F; ++o) acc[o] = b2[o];
        for (int k = 0; k < HID; ++k) {
            float p = psum[(long long)gg * HID + k] / c;
            #pragma unroll
            for (int o = 0; o < OUT_F; ++o)
                acc[o] = fmaf(p, w2[k * OUT_F + o], acc[o]);
        }
        #pragma unroll
        for (int o = 0; o < OUT_F; ++o) out[gg * OUT_F + o] = acc[o];
    }
}

static inline size_t align256(size_t x) { return (x + 255) & ~(size_t)255; }

extern "C" void kernel_launch(void* const* d_in, const int* in_sizes, int n_in,
                              void* d_out, int out_size, void* d_ws, size_t ws_size,
                              hipStream_t stream) {
    const float* x     = (const float*)d_in[0];
    const void*  eidx  = d_in[1];
    const void*  batch = d_in[2];
    const float* w1    = (const float*)d_in[3];
    const float* b1    = (const float*)d_in[4];
    const float* convw = (const float*)d_in[5];
    const float* w2    = (const float*)d_in[6];
    const float* b2    = (const float*)d_in[7];
    float* out = (float*)d_out;

    int N = in_sizes[0] / IN_F;
    int E = in_sizes[1] / 2;
    int nbuk = (N + BNODES - 1) >> BSH;

    char* ws = (char*)d_ws;
    float* dinv    = (float*)ws;                ws += align256((size_t)N * 4);
    unsigned short* h0  = (unsigned short*)ws;  ws += align256((size_t)N * HID * 2);
    unsigned short* hs0 = (unsigned short*)ws;  ws += align256((size_t)N * HID * 2);
    unsigned short* hb  = (unsigned short*)ws;  ws += align256((size_t)N * HID * 2);
    float* psum    = (float*)ws;                ws += align256((size_t)NG * HID * 4);
    float* pcnt    = (float*)ws;                ws += align256((size_t)NG * 4);
    int*   rowptr  = (int*)ws;                  ws += align256((size_t)(N + 1) * 4);
    int*   csr_src = (int*)ws;                  ws += align256((size_t)E * 4);
    int*   gcur    = (int*)ws;                  ws += align256((size_t)nbuk * 4);
    unsigned short* w16t = (unsigned short*)ws; ws += align256((size_t)NLAYER * HID * HID * 2);
    unsigned* bucketed = (unsigned*)ws;         ws += align256((size_t)nbuk * CAP * 4);
    int*   flag    = (int*)ws;                  ws += align256(4);
    int*   done    = (int*)ws;

    // 1. detect + zero gcur/psum/pcnt/done + W->f16^T
    k_detect<<<1, 256, 0, stream>>>((const unsigned int*)eidx, 4096, flag, gcur, nbuk,
                                    convw, w16t, psum, pcnt, done);

    // 2. CSR build: block counting-sort -> per-bucket sort (self-prefix)
    if (nbuk <= NBUK_MAX)
        k_bucket2<<<(E + EPB - 1) / EPB, 1024, 0, stream>>>(eidx, flag, E, nbuk,
                                                            gcur, bucketed);
    else
        k_bucket_fb<<<(E + 255) / 256, 256, 0, stream>>>(eidx, flag, E, gcur, bucketed);
    k_bfill<<<nbuk, 256, 0, stream>>>(gcur, bucketed, rowptr, dinv, csr_src, N, nbuk);

    // 3. lin1 (MFMA) -> h0 (raw f16) + hs0 (scaled f16)
    k_lin1<<<(N + LNB - 1) / LNB, 256, 0, stream>>>(x, w1, b1, dinv, h0, hs0, N);

    // 4. three fused GCN2 layers: hs0 -> hb -> hs0 -> hb(raw)
    int nlb = (N + 15) / 16;
    float beta0 = logf(0.5f / 1.0f + 1.0f);
    float beta1 = logf(0.5f / 2.0f + 1.0f);
    float beta2 = logf(0.5f / 3.0f + 1.0f);
    k_layer<<<nlb, 256, 0, stream>>>(rowptr, csr_src, dinv, hs0, h0,
                                     w16t + 0 * HID * HID, beta0, 1, hb, N);
    k_layer<<<nlb, 256, 0, stream>>>(rowptr, csr_src, dinv, hb, h0,
                                     w16t + 1 * HID * HID, beta1, 1, hs0, N);
    k_layer<<<nlb, 256, 0, stream>>>(rowptr, csr_src, dinv, hs0, h0,
                                     w16t + 2 * HID * HID, beta2, 0, hb, N);

    // 5. pooling + fused final linear (last-block-done)
    int npb = (N + POOL_CHUNK - 1) / POOL_CHUNK;
    k_pool<<<npb, 256, 0, stream>>>(hb, batch, flag, psum, pcnt, N,
                                    w2, b2, out, done, npb);
}